// Round 5
// baseline (634.956 us; speedup 1.0000x reference)
//
#include <hip/hip_runtime.h>
#include <hip/hip_bf16.h>

#define N_NODES 100000
#define N_EDGES 600000
#define N_GRAPHS 64
#define D 128

#define NBLK_SCAN ((N_NODES + 255) / 256)  // 391

// ---------------- CSR build ----------------

__global__ void count_deg_k(const int* __restrict__ col, int* __restrict__ cnt) {
    int e = blockIdx.x * blockDim.x + threadIdx.x;
    if (e < N_EDGES) atomicAdd(&cnt[col[e]], 1);
}

__global__ __launch_bounds__(256) void partial_k(const int* __restrict__ cnt,
                                                 int* __restrict__ psum) {
    int i = blockIdx.x * 256 + threadIdx.x;
    int v = (i < N_NODES) ? cnt[i] : 0;
#pragma unroll
    for (int d = 32; d > 0; d >>= 1) v += __shfl_down(v, d, 64);
    __shared__ int ws[4];
    if ((threadIdx.x & 63) == 0) ws[threadIdx.x >> 6] = v;
    __syncthreads();
    if (threadIdx.x == 0) psum[blockIdx.x] = ws[0] + ws[1] + ws[2] + ws[3];
}

__global__ __launch_bounds__(512) void scanpart_k(int* __restrict__ psum) {
    __shared__ int ls[512];
    int t = threadIdx.x;
    int v = (t < NBLK_SCAN) ? psum[t] : 0;
    ls[t] = v;
    __syncthreads();
    for (int d = 1; d < 512; d <<= 1) {
        int u = (t >= d) ? ls[t - d] : 0;
        __syncthreads();
        ls[t] += u;
        __syncthreads();
    }
    if (t < NBLK_SCAN) psum[t] = ls[t] - v;  // exclusive
}

__global__ __launch_bounds__(256) void scan_scatter_k(const int* __restrict__ cnt,
                                                      const int* __restrict__ psum,
                                                      int* __restrict__ start) {
    int b = blockIdx.x, t = threadIdx.x;
    int i = b * 256 + t;
    int v = (i < N_NODES) ? cnt[i] : 0;
    __shared__ int ls[256];
    ls[t] = v;
    __syncthreads();
    for (int d = 1; d < 256; d <<= 1) {
        int u = (t >= d) ? ls[t - d] : 0;
        __syncthreads();
        ls[t] += u;
        __syncthreads();
    }
    int incl = ls[t];
    int off = psum[b];
    if (i < N_NODES) start[i] = off + incl - v;
    if (i == N_NODES - 1) start[N_NODES] = off + incl;
}

__global__ void fill_csr_k(const int* __restrict__ row, const int* __restrict__ col,
                           const int* __restrict__ start, int* __restrict__ fill,
                           int* __restrict__ esrc) {
    int e = blockIdx.x * blockDim.x + threadIdx.x;
    if (e < N_EDGES) {
        int c = col[e];
        int p = atomicAdd(&fill[c], 1);
        esrc[start[c] + p] = row[e];
    }
}

// ---------------- graph segment bounds (batch is sorted) ----------------

__global__ __launch_bounds__(128) void bounds_k(const int* __restrict__ batch,
                                                int* __restrict__ gstart) {
    int g = threadIdx.x;
    if (g > N_GRAPHS) return;
    int lo = 0, hi = N_NODES;
    while (lo < hi) {
        int mid = (lo + hi) >> 1;
        if (batch[mid] < g) lo = mid + 1; else hi = mid;
    }
    gstart[g] = lo;
}

// ---------------- GEMM: out[i][j] = bias[j] + sum_k in[i][k]*W[j][k] ----------------
// 2-phase pipelined K-tiling (KT=32), LDS 64KB -> 2 blocks/CU, global_load_lds
// staging. Swizzle: LDS slot q of row j holds global float4-chunk (q ^ s4(j)),
// s4(j) = ((j>>3) ^ j) & 7. Reads XOR with the same s4(row being read):
//   A row 8*ty+i  -> s4 = (ty^i)&7   (4 distinct slots/wave -> conflict-free)
//   W row tx+16*r -> s4 = (((tx>>3)+2r)^tx)&7 (each slot 2x over 16 tx -> free)

#define BM 128
#define KT 32
#define TILE_F (BM * KT)  // 4096 floats = 16KB

__device__ __forceinline__ void stage_tile(const float* __restrict__ G, int ld,
                                           float* lds, int grow0, int kt,
                                           int nrows, int tid) {
    int l = tid & 63, wv = tid >> 6;
#pragma unroll
    for (int i = 0; i < 4; ++i) {
        int row = i * 32 + wv * 8 + (l >> 3);
        int q = l & 7;
        int s4 = ((row >> 3) ^ row) & 7;
        int grow = grow0 + row;
        const float* gp = G + (size_t)grow * ld + kt * KT + ((q ^ s4) << 2);
        float* lp = lds + i * 1024 + wv * 256;  // wave-uniform base; HW adds lane*16
        if (grow < nrows)
            __builtin_amdgcn_global_load_lds(
                (const __attribute__((address_space(1))) void*)gp,
                (__attribute__((address_space(3))) void*)lp, 16, 0, 0);
    }
}

__global__ __launch_bounds__(256, 2) void gemm_k(const float* __restrict__ A,
                                                 const float* __restrict__ W,
                                                 const float* __restrict__ bias,
                                                 float* __restrict__ out, int nrows) {
    __shared__ float sA[2][TILE_F];
    __shared__ float sW[2][TILE_F];
    const int tid = threadIdx.x;
    const int bm0 = blockIdx.x * BM;
    const int tx = tid & 15, ty = tid >> 4;

    float acc[8][8];
#pragma unroll
    for (int i = 0; i < 8; ++i)
#pragma unroll
        for (int r = 0; r < 8; ++r) acc[i][r] = 0.f;

    float bv[8];
#pragma unroll
    for (int r = 0; r < 8; ++r) bv[r] = bias[tx + 16 * r];

    // prologue: stage tile 0
    stage_tile(A, D, sA[0], bm0, 0, nrows, tid);
    stage_tile(W, D, sW[0], 0, 0, D, tid);
    __syncthreads();

    int cur = 0;
    for (int t = 0; t < D / KT; ++t) {
        if (t < D / KT - 1) {
            stage_tile(A, D, sA[cur ^ 1], bm0, t + 1, nrows, tid);
            stage_tile(W, D, sW[cur ^ 1], 0, t + 1, D, tid);
        }
        const float* bA = sA[cur];
        const float* bW = sW[cur];
#pragma unroll
        for (int k0 = 0; k0 < KT; k0 += 4) {
            int c4 = k0 >> 2;
            float4 a[8], w[8];
#pragma unroll
            for (int i = 0; i < 8; ++i) {
                int slot = c4 ^ ((ty ^ i) & 7);
                a[i] = *reinterpret_cast<const float4*>(
                    &bA[(8 * ty + i) * KT + (slot << 2)]);
            }
#pragma unroll
            for (int r = 0; r < 8; ++r) {
                int slot = c4 ^ ((((tx >> 3) + 2 * r) ^ tx) & 7);
                w[r] = *reinterpret_cast<const float4*>(
                    &bW[(tx + 16 * r) * KT + (slot << 2)]);
            }
#pragma unroll
            for (int i = 0; i < 8; ++i)
#pragma unroll
                for (int r = 0; r < 8; ++r) {
                    acc[i][r] = fmaf(a[i].x, w[r].x, acc[i][r]);
                    acc[i][r] = fmaf(a[i].y, w[r].y, acc[i][r]);
                    acc[i][r] = fmaf(a[i].z, w[r].z, acc[i][r]);
                    acc[i][r] = fmaf(a[i].w, w[r].w, acc[i][r]);
                }
        }
        __syncthreads();  // drains next-tile loads + lds reads
        cur ^= 1;
    }

#pragma unroll
    for (int i = 0; i < 8; ++i) {
        int grow = bm0 + ty * 8 + i;
        if (grow < nrows) {
            float* orow = &out[(size_t)grow * D];
#pragma unroll
            for (int r = 0; r < 8; ++r) orow[tx + 16 * r] = acc[i][r] + bv[r];
        }
    }
}

// ---------------- Aggregation: out[i] = t[i] + sum_{e: col==i} t[src[e]] ----------------

__global__ __launch_bounds__(128) void aggregate_k(const float* __restrict__ t,
                                                   const int* __restrict__ start,
                                                   const int* __restrict__ esrc,
                                                   float* __restrict__ out, int do_relu) {
    int node = blockIdx.x;
    int d = threadIdx.x;
    int s = start[node], e = start[node + 1];
    float acc = t[(size_t)node * D + d];  // self loop
    int i = s;
    for (; i + 1 < e; i += 2) {
        int s0 = esrc[i], s1 = esrc[i + 1];
        float a = t[(size_t)s0 * D + d];
        float b = t[(size_t)s1 * D + d];
        acc += a + b;
    }
    if (i < e) acc += t[(size_t)esrc[i] * D + d];
    if (do_relu) acc = fmaxf(acc, 0.f);
    out[(size_t)node * D + d] = acc;
}

// ---------------- Pooling ----------------

__global__ __launch_bounds__(128) void pool_k(const float* __restrict__ h,
                                              const int* __restrict__ batch,
                                              float* __restrict__ pooled) {
    int d = threadIdx.x;
    int n0 = blockIdx.x * 32;
    int nend = min(n0 + 32, N_NODES);
    int curg = batch[n0];
    float acc = 0.f;
    for (int n = n0; n < nend; ++n) {
        int g = batch[n];
        if (g != curg) {
            unsafeAtomicAdd(&pooled[curg * D + d], acc);
            acc = 0.f;
            curg = g;
        }
        acc += h[(size_t)n * D + d];
    }
    unsafeAtomicAdd(&pooled[curg * D + d], acc);
}

__global__ __launch_bounds__(128) void final_k(const float* __restrict__ pooled,
                                               const int* __restrict__ gstart,
                                               const float* __restrict__ Wc,
                                               const float* __restrict__ bc,
                                               float* __restrict__ out) {
    int g = blockIdx.x;
    int d = threadIdx.x;
    float c = (float)max(gstart[g + 1] - gstart[g], 1);
    float v = pooled[g * D + d] / c * Wc[d];
    __shared__ float red[128];
    red[d] = v;
    __syncthreads();
    for (int s = 64; s > 0; s >>= 1) {
        if (d < s) red[d] += red[d + s];
        __syncthreads();
    }
    if (d == 0) out[g] = 1.f / (1.f + expf(-(red[0] + bc[0])));
}

// ---------------- Launch ----------------

extern "C" void kernel_launch(void* const* d_in, const int* in_sizes, int n_in,
                              void* d_out, int out_size, void* d_ws, size_t ws_size,
                              hipStream_t stream) {
    const float* x   = (const float*)d_in[0];
    const int* ei    = (const int*)d_in[1];   // [2,600000] int32
    const int* batch = (const int*)d_in[2];
    const float* W1  = (const float*)d_in[3];
    const float* b1  = (const float*)d_in[4];
    const float* W2  = (const float*)d_in[5];
    const float* b2  = (const float*)d_in[6];
    const float* W3  = (const float*)d_in[7];
    const float* b3  = (const float*)d_in[8];
    const float* W4  = (const float*)d_in[9];
    const float* b4  = (const float*)d_in[10];
    const float* Wc  = (const float*)d_in[11];
    const float* bc  = (const float*)d_in[12];
    float* out = (float*)d_out;

    const int* row = ei;             // sources
    const int* col = ei + N_EDGES;   // targets

    char* p = (char*)d_ws;
    float* t = (float*)p;      p += (size_t)N_NODES * D * 4;   // 51.2 MB
    float* h = (float*)p;      p += (size_t)N_NODES * D * 4;   // 51.2 MB
    int* esrc = (int*)p;       p += (size_t)N_EDGES * 4;       // 2.4 MB
    int* cstart = (int*)p;     p += ((N_NODES + 1) * 4 + 15) / 16 * 16;
    int* cfill = (int*)p;      p += (size_t)N_NODES * 4;
    int* psum = (int*)p;       p += ((NBLK_SCAN + 3) / 4) * 16;
    float* pooled = (float*)p; p += N_GRAPHS * D * 4;
    int* gstart = (int*)p;     p += 256;

    // ---- CSR build ----
    hipMemsetAsync(cfill, 0, (size_t)N_NODES * 4, stream);
    count_deg_k<<<(N_EDGES + 255) / 256, 256, 0, stream>>>(col, cfill);
    partial_k<<<NBLK_SCAN, 256, 0, stream>>>(cfill, psum);
    scanpart_k<<<1, 512, 0, stream>>>(psum);
    scan_scatter_k<<<NBLK_SCAN, 256, 0, stream>>>(cfill, psum, cstart);
    hipMemsetAsync(cfill, 0, (size_t)N_NODES * 4, stream);
    fill_csr_k<<<(N_EDGES + 255) / 256, 256, 0, stream>>>(row, col, cstart, cfill, esrc);

    // ---- graph bounds ----
    bounds_k<<<1, 128, 0, stream>>>(batch, gstart);

    const int ggrid = (N_NODES + BM - 1) / BM;  // 782

    // ---- Layer 1 ----
    gemm_k<<<ggrid, 256, 0, stream>>>(x, W1, b1, t, N_NODES);
    aggregate_k<<<N_NODES, 128, 0, stream>>>(t, cstart, esrc, h, 1);
    // ---- Layer 2 ----
    gemm_k<<<ggrid, 256, 0, stream>>>(h, W2, b2, t, N_NODES);
    aggregate_k<<<N_NODES, 128, 0, stream>>>(t, cstart, esrc, h, 1);
    // ---- Layer 3 ----
    gemm_k<<<ggrid, 256, 0, stream>>>(h, W3, b3, t, N_NODES);
    aggregate_k<<<N_NODES, 128, 0, stream>>>(t, cstart, esrc, h, 1);
    // ---- Layer 4 ----
    gemm_k<<<ggrid, 256, 0, stream>>>(h, W4, b4, t, N_NODES);
    aggregate_k<<<N_NODES, 128, 0, stream>>>(t, cstart, esrc, h, 0);

    // ---- Pooling + head ----
    hipMemsetAsync(pooled, 0, (size_t)N_GRAPHS * D * 4, stream);
    pool_k<<<(N_NODES + 31) / 32, 128, 0, stream>>>(h, batch, pooled);
    final_k<<<N_GRAPHS, 128, 0, stream>>>(pooled, gstart, Wc, bc, out);
}

// Round 6
// 520.303 us; speedup vs baseline: 1.2204x; 1.2204x over previous
//
#include <hip/hip_runtime.h>
#include <hip/hip_bf16.h>

#define N_NODES 100000
#define N_EDGES 600000
#define N_GRAPHS 64
#define D 128

#define NBLK_SCAN ((N_NODES + 255) / 256)  // 391

// ---------------- CSR build ----------------

__global__ void count_deg_k(const int* __restrict__ col, int* __restrict__ cnt) {
    int e = blockIdx.x * blockDim.x + threadIdx.x;
    if (e < N_EDGES) atomicAdd(&cnt[col[e]], 1);
}

__global__ __launch_bounds__(256) void partial_k(const int* __restrict__ cnt,
                                                 int* __restrict__ psum) {
    int i = blockIdx.x * 256 + threadIdx.x;
    int v = (i < N_NODES) ? cnt[i] : 0;
#pragma unroll
    for (int d = 32; d > 0; d >>= 1) v += __shfl_down(v, d, 64);
    __shared__ int ws[4];
    if ((threadIdx.x & 63) == 0) ws[threadIdx.x >> 6] = v;
    __syncthreads();
    if (threadIdx.x == 0) psum[blockIdx.x] = ws[0] + ws[1] + ws[2] + ws[3];
}

__global__ __launch_bounds__(512) void scanpart_k(int* __restrict__ psum) {
    __shared__ int ls[512];
    int t = threadIdx.x;
    int v = (t < NBLK_SCAN) ? psum[t] : 0;
    ls[t] = v;
    __syncthreads();
    for (int d = 1; d < 512; d <<= 1) {
        int u = (t >= d) ? ls[t - d] : 0;
        __syncthreads();
        ls[t] += u;
        __syncthreads();
    }
    if (t < NBLK_SCAN) psum[t] = ls[t] - v;  // exclusive
}

__global__ __launch_bounds__(256) void scan_scatter_k(const int* __restrict__ cnt,
                                                      const int* __restrict__ psum,
                                                      int* __restrict__ start) {
    int b = blockIdx.x, t = threadIdx.x;
    int i = b * 256 + t;
    int v = (i < N_NODES) ? cnt[i] : 0;
    __shared__ int ls[256];
    ls[t] = v;
    __syncthreads();
    for (int d = 1; d < 256; d <<= 1) {
        int u = (t >= d) ? ls[t - d] : 0;
        __syncthreads();
        ls[t] += u;
        __syncthreads();
    }
    int incl = ls[t];
    int off = psum[b];
    if (i < N_NODES) start[i] = off + incl - v;
    if (i == N_NODES - 1) start[N_NODES] = off + incl;
}

__global__ void fill_csr_k(const int* __restrict__ row, const int* __restrict__ col,
                           const int* __restrict__ start, int* __restrict__ fill,
                           int* __restrict__ esrc) {
    int e = blockIdx.x * blockDim.x + threadIdx.x;
    if (e < N_EDGES) {
        int c = col[e];
        int p = atomicAdd(&fill[c], 1);
        esrc[start[c] + p] = row[e];
    }
}

// ---------------- graph segment bounds (batch is sorted) ----------------

__global__ __launch_bounds__(128) void bounds_k(const int* __restrict__ batch,
                                                int* __restrict__ gstart) {
    int g = threadIdx.x;
    if (g > N_GRAPHS) return;
    int lo = 0, hi = N_NODES;
    while (lo < hi) {
        int mid = (lo + hi) >> 1;
        if (batch[mid] < g) lo = mid + 1; else hi = mid;
    }
    gstart[g] = lo;
}

// ---------------- GEMM: out[i][j] = bias[j] + sum_k in[i][k]*W[j][k] ----------------
// 2-phase pipelined K-tiling (KT=32), LDS 64KB -> 2 blocks/CU, global_load_lds
// staging. Swizzle: LDS slot q of row j holds global float4-chunk (q ^ s4(j)),
// s4(j) = ((j>>3) ^ j) & 7.
//   A row 8*ty+i  -> s4 = (ty^i)&7       (4 broadcast addrs/wave -> free)
//   W row 8*tx+r  -> s4 = (tx^r)&7       (8 slot-groups x 2-way -> free)
// Output: thread owns rows 8*ty+i, cols 8*tx..8*tx+7 -> float4 stores (full
// 512B/row per wave; round-5's tx+16r scatter caused 67MB partial-line writes).

#define BM 128
#define KT 32
#define TILE_F (BM * KT)  // 4096 floats = 16KB

__device__ __forceinline__ void stage_tile(const float* __restrict__ G, int ld,
                                           float* lds, int grow0, int kt,
                                           int nrows, int tid) {
    int l = tid & 63, wv = tid >> 6;
#pragma unroll
    for (int i = 0; i < 4; ++i) {
        int row = i * 32 + wv * 8 + (l >> 3);
        int q = l & 7;
        int s4 = ((row >> 3) ^ row) & 7;
        int grow = grow0 + row;
        const float* gp = G + (size_t)grow * ld + kt * KT + ((q ^ s4) << 2);
        float* lp = lds + i * 1024 + wv * 256;  // wave-uniform base; HW adds lane*16
        if (grow < nrows)
            __builtin_amdgcn_global_load_lds(
                (const __attribute__((address_space(1))) void*)gp,
                (__attribute__((address_space(3))) void*)lp, 16, 0, 0);
    }
}

__global__ __launch_bounds__(256, 2) void gemm_k(const float* __restrict__ A,
                                                 const float* __restrict__ W,
                                                 const float* __restrict__ bias,
                                                 float* __restrict__ out, int nrows) {
    __shared__ float sA[2][TILE_F];
    __shared__ float sW[2][TILE_F];
    const int tid = threadIdx.x;
    const int bm0 = blockIdx.x * BM;
    const int tx = tid & 15, ty = tid >> 4;

    float acc[8][8];
#pragma unroll
    for (int i = 0; i < 8; ++i)
#pragma unroll
        for (int r = 0; r < 8; ++r) acc[i][r] = 0.f;

    float bv[8];
#pragma unroll
    for (int r = 0; r < 8; ++r) bv[r] = bias[8 * tx + r];

    // prologue: stage tile 0
    stage_tile(A, D, sA[0], bm0, 0, nrows, tid);
    stage_tile(W, D, sW[0], 0, 0, D, tid);
    __syncthreads();

    int cur = 0;
    for (int t = 0; t < D / KT; ++t) {
        if (t < D / KT - 1) {
            stage_tile(A, D, sA[cur ^ 1], bm0, t + 1, nrows, tid);
            stage_tile(W, D, sW[cur ^ 1], 0, t + 1, D, tid);
        }
        const float* bA = sA[cur];
        const float* bW = sW[cur];
#pragma unroll
        for (int k0 = 0; k0 < KT; k0 += 4) {
            int c4 = k0 >> 2;
            float4 a[8], w[8];
#pragma unroll
            for (int i = 0; i < 8; ++i) {
                int slot = c4 ^ ((ty ^ i) & 7);
                a[i] = *reinterpret_cast<const float4*>(
                    &bA[(8 * ty + i) * KT + (slot << 2)]);
            }
#pragma unroll
            for (int r = 0; r < 8; ++r) {
                int slot = c4 ^ ((tx ^ r) & 7);
                w[r] = *reinterpret_cast<const float4*>(
                    &bW[(8 * tx + r) * KT + (slot << 2)]);
            }
#pragma unroll
            for (int i = 0; i < 8; ++i)
#pragma unroll
                for (int r = 0; r < 8; ++r) {
                    acc[i][r] = fmaf(a[i].x, w[r].x, acc[i][r]);
                    acc[i][r] = fmaf(a[i].y, w[r].y, acc[i][r]);
                    acc[i][r] = fmaf(a[i].z, w[r].z, acc[i][r]);
                    acc[i][r] = fmaf(a[i].w, w[r].w, acc[i][r]);
                }
        }
        __syncthreads();  // drains next-tile loads + lds reads
        cur ^= 1;
    }

#pragma unroll
    for (int i = 0; i < 8; ++i) {
        int grow = bm0 + ty * 8 + i;
        if (grow < nrows) {
            float* orow = &out[(size_t)grow * D + 8 * tx];
            float4 o0 = make_float4(acc[i][0] + bv[0], acc[i][1] + bv[1],
                                    acc[i][2] + bv[2], acc[i][3] + bv[3]);
            float4 o1 = make_float4(acc[i][4] + bv[4], acc[i][5] + bv[5],
                                    acc[i][6] + bv[6], acc[i][7] + bv[7]);
            *reinterpret_cast<float4*>(orow) = o0;
            *reinterpret_cast<float4*>(orow + 4) = o1;
        }
    }
}

// ---------------- Aggregation: out[i] = t[i] + sum_{e: col==i} t[src[e]] ----------------

__global__ __launch_bounds__(128) void aggregate_k(const float* __restrict__ t,
                                                   const int* __restrict__ start,
                                                   const int* __restrict__ esrc,
                                                   float* __restrict__ out, int do_relu) {
    int node = blockIdx.x;
    int d = threadIdx.x;
    int s = start[node], e = start[node + 1];
    float acc = t[(size_t)node * D + d];  // self loop
    int i = s;
    for (; i + 1 < e; i += 2) {
        int s0 = esrc[i], s1 = esrc[i + 1];
        float a = t[(size_t)s0 * D + d];
        float b = t[(size_t)s1 * D + d];
        acc += a + b;
    }
    if (i < e) acc += t[(size_t)esrc[i] * D + d];
    if (do_relu) acc = fmaxf(acc, 0.f);
    out[(size_t)node * D + d] = acc;
}

// ---------------- Collapsed layer 4 + pool + head ----------------
// logit_g = (1/c_g) * sum_{i in g} [ s[i] + sum_{src->i} s[src] + (1+deg_i)*beta ] + bc
// where s[i] = h3[i] . v,  v = Wc @ W4  (128-vec),  beta = Wc . b4.

__global__ __launch_bounds__(128) void vbeta_k(const float* __restrict__ W4,
                                               const float* __restrict__ b4,
                                               const float* __restrict__ Wc,
                                               float* __restrict__ vbeta) {
    int k = threadIdx.x;
    float acc = 0.f;
    for (int j = 0; j < D; ++j) acc = fmaf(Wc[j], W4[j * D + k], acc);
    vbeta[k] = acc;
    // beta = sum_j Wc[j]*b4[j]
    __shared__ float red[128];
    red[k] = Wc[k] * b4[k];
    __syncthreads();
    for (int st = 64; st > 0; st >>= 1) {
        if (k < st) red[k] += red[k + st];
        __syncthreads();
    }
    if (k == 0) vbeta[D] = red[0];
}

// s[i] = h[i] . v   (one wave per row, float2 per lane)
__global__ __launch_bounds__(256) void matvec_k(const float* __restrict__ h,
                                                const float* __restrict__ vbeta,
                                                float* __restrict__ s) {
    int wid = threadIdx.x >> 6, lane = threadIdx.x & 63;
    int row = blockIdx.x * 4 + wid;
    const float2 hv = *reinterpret_cast<const float2*>(&h[(size_t)row * D + lane * 2]);
    const float2 vv = *reinterpret_cast<const float2*>(&vbeta[lane * 2]);
    float dot = fmaf(hv.x, vv.x, hv.y * vv.y);
#pragma unroll
    for (int d = 32; d > 0; d >>= 1) dot += __shfl_down(dot, d, 64);
    if (lane == 0) s[row] = dot;
}

// a[i] = s[i] + sum_{csr} s[src] + (1+deg)*beta
__global__ __launch_bounds__(256) void sagg_k(const float* __restrict__ s,
                                              const int* __restrict__ start,
                                              const int* __restrict__ esrc,
                                              const float* __restrict__ vbeta,
                                              float* __restrict__ a) {
    int i = blockIdx.x * 256 + threadIdx.x;
    if (i >= N_NODES) return;
    int s0 = start[i], s1 = start[i + 1];
    float beta = vbeta[D];
    float acc = s[i] + (float)(1 + s1 - s0) * beta;
    for (int e = s0; e < s1; ++e) acc += s[esrc[e]];
    a[i] = acc;
}

// per-graph mean + sigmoid
__global__ __launch_bounds__(256) void spool_k(const float* __restrict__ a,
                                               const int* __restrict__ gstart,
                                               const float* __restrict__ bc,
                                               float* __restrict__ out) {
    int g = blockIdx.x;
    int lo = gstart[g], hi = gstart[g + 1];
    float acc = 0.f;
    for (int i = lo + threadIdx.x; i < hi; i += 256) acc += a[i];
    __shared__ float red[256];
    red[threadIdx.x] = acc;
    __syncthreads();
    for (int st = 128; st > 0; st >>= 1) {
        if (threadIdx.x < st) red[threadIdx.x] += red[threadIdx.x + st];
        __syncthreads();
    }
    if (threadIdx.x == 0) {
        float c = (float)max(hi - lo, 1);
        out[g] = 1.f / (1.f + expf(-(red[0] / c + bc[0])));
    }
}

// ---------------- Launch ----------------

extern "C" void kernel_launch(void* const* d_in, const int* in_sizes, int n_in,
                              void* d_out, int out_size, void* d_ws, size_t ws_size,
                              hipStream_t stream) {
    const float* x   = (const float*)d_in[0];
    const int* ei    = (const int*)d_in[1];   // [2,600000] int32
    const int* batch = (const int*)d_in[2];
    const float* W1  = (const float*)d_in[3];
    const float* b1  = (const float*)d_in[4];
    const float* W2  = (const float*)d_in[5];
    const float* b2  = (const float*)d_in[6];
    const float* W3  = (const float*)d_in[7];
    const float* b3  = (const float*)d_in[8];
    const float* W4  = (const float*)d_in[9];
    const float* b4  = (const float*)d_in[10];
    const float* Wc  = (const float*)d_in[11];
    const float* bc  = (const float*)d_in[12];
    float* out = (float*)d_out;

    const int* row = ei;             // sources
    const int* col = ei + N_EDGES;   // targets

    char* p = (char*)d_ws;
    float* t = (float*)p;      p += (size_t)N_NODES * D * 4;   // 51.2 MB
    float* h = (float*)p;      p += (size_t)N_NODES * D * 4;   // 51.2 MB
    int* esrc = (int*)p;       p += (size_t)N_EDGES * 4;       // 2.4 MB
    int* cstart = (int*)p;     p += ((N_NODES + 1) * 4 + 15) / 16 * 16;
    int* cfill = (int*)p;      p += (size_t)N_NODES * 4;
    int* psum = (int*)p;       p += ((NBLK_SCAN + 3) / 4) * 16;
    int* gstart = (int*)p;     p += 256;

    // t is free after the 3rd aggregate consumes it -> reuse for scalar path
    float* vbeta = t;                 // 129 floats
    float* s_arr = t + 256;           // 100k floats
    float* a_arr = t + 256 + N_NODES; // 100k floats

    // ---- CSR build ----
    hipMemsetAsync(cfill, 0, (size_t)N_NODES * 4, stream);
    count_deg_k<<<(N_EDGES + 255) / 256, 256, 0, stream>>>(col, cfill);
    partial_k<<<NBLK_SCAN, 256, 0, stream>>>(cfill, psum);
    scanpart_k<<<1, 512, 0, stream>>>(psum);
    scan_scatter_k<<<NBLK_SCAN, 256, 0, stream>>>(cfill, psum, cstart);
    hipMemsetAsync(cfill, 0, (size_t)N_NODES * 4, stream);
    fill_csr_k<<<(N_EDGES + 255) / 256, 256, 0, stream>>>(row, col, cstart, cfill, esrc);

    // ---- graph bounds ----
    bounds_k<<<1, 128, 0, stream>>>(batch, gstart);

    const int ggrid = (N_NODES + BM - 1) / BM;  // 782

    // ---- Layers 1-3 ----
    gemm_k<<<ggrid, 256, 0, stream>>>(x, W1, b1, t, N_NODES);
    aggregate_k<<<N_NODES, 128, 0, stream>>>(t, cstart, esrc, h, 1);
    gemm_k<<<ggrid, 256, 0, stream>>>(h, W2, b2, t, N_NODES);
    aggregate_k<<<N_NODES, 128, 0, stream>>>(t, cstart, esrc, h, 1);
    gemm_k<<<ggrid, 256, 0, stream>>>(h, W3, b3, t, N_NODES);
    aggregate_k<<<N_NODES, 128, 0, stream>>>(t, cstart, esrc, h, 1);

    // ---- Collapsed layer 4 + pool + head ----
    vbeta_k<<<1, 128, 0, stream>>>(W4, b4, Wc, vbeta);
    matvec_k<<<N_NODES / 4, 256, 0, stream>>>(h, vbeta, s_arr);
    sagg_k<<<(N_NODES + 255) / 256, 256, 0, stream>>>(s_arr, cstart, esrc, vbeta, a_arr);
    spool_k<<<N_GRAPHS, 256, 0, stream>>>(a_arr, gstart, bc, out);
}